// Round 1
// baseline (417.140 us; speedup 1.0000x reference)
//
#include <hip/hip_runtime.h>
#include <hip/hip_bf16.h>
#include <stdint.h>

// Problem constants (reference: B,TQ,TK,D,DV = 8,2048,2048,1024,1024)
#define B_  8
#define TQ_ 2048
#define TK_ 2048
#define D_  1024
#define DV_ 1024

typedef __attribute__((ext_vector_type(8))) short  short8;
typedef __attribute__((ext_vector_type(4))) float  floatx4;

__device__ __forceinline__ void async_copy16(const void* g, void* l) {
  // 16B-per-lane global->LDS DMA. LDS dest must be wave-uniform-base + lane*16.
  __builtin_amdgcn_global_load_lds(
      (const __attribute__((address_space(1))) unsigned int*)g,
      (__attribute__((address_space(3))) unsigned int*)l,
      16, 0, 0);
}

__device__ __forceinline__ ushort f2bf(float f) {
  union { __hip_bfloat16 b; ushort u; } cv;
  cv.b = __float2bfloat16(f);
  return cv.u;
}

__device__ __forceinline__ float bf2f(ushort u) {
  union { ushort u; __hip_bfloat16 b; } cv;
  cv.u = u;
  return __bfloat162float(cv.b);
}

// ---------------- conversion kernels ----------------

// fp32 -> bf16, same layout, 4 elems/thread
__global__ void cvt_bf16(const float4* __restrict__ in, ushort4* __restrict__ out, int n4) {
  int i = blockIdx.x * 256 + threadIdx.x;
  if (i < n4) {
    float4 f = in[i];
    ushort4 o;
    o.x = f2bf(f.x); o.y = f2bf(f.y); o.z = f2bf(f.z); o.w = f2bf(f.w);
    out[i] = o;
  }
}

// in: [z][R][C] fp32  ->  out: [z][C][R] bf16 (tiled 32x32 transpose)
__global__ void transpose_cvt(const float* __restrict__ in, ushort* __restrict__ out,
                              int R, int C) {
  __shared__ float tile[32][33];
  int tx = threadIdx.x, ty = threadIdx.y;          // block (32,8)
  int c0 = blockIdx.x * 32, r0 = blockIdx.y * 32;
  size_t zoff = (size_t)blockIdx.z * R * C;
  #pragma unroll
  for (int i = 0; i < 4; i++)
    tile[ty + i * 8][tx] = in[zoff + (size_t)(r0 + ty + i * 8) * C + (c0 + tx)];
  __syncthreads();
  #pragma unroll
  for (int i = 0; i < 4; i++)
    out[zoff + (size_t)(c0 + ty + i * 8) * R + (r0 + tx)] = f2bf(tile[tx][ty + i * 8]);
}

// ---------------- GEMM core (m97 recipe) ----------------
// C[128x128] per block, 256 threads = 4 waves in 2x2, each wave 64x64 = 4x4
// mfma_f32_16x16x32_bf16 tiles. A: [M][KDIM] bf16 row-major. B^T: [N][KDIM]
// bf16 row-major. BK=32, LDS tiles 128x32 (no padding: global_load_lds is
// lane-linear). A-frag: lane holds A[m=lane&15][k=(lane>>4)*8+j].
template <int KDIM>
__device__ __forceinline__ void gemm_core(const ushort* __restrict__ Ab,
                                          const ushort* __restrict__ Bb,
                                          ushort* ldsA, ushort* ldsB,
                                          int bm0, int bn0,
                                          floatx4 (&acc)[4][4]) {
  const int t    = threadIdx.x;
  const int lane = t & 63;
  const int w    = t >> 6;
  const int wm   = w >> 1, wn = w & 1;
  const int lc   = lane & 15;
  const int kg   = (lane >> 4) * 16;  // byte offset of this lane's k-group in a 64B row

  // staging: each thread DMAs 2x16B for A and 2x16B for B per K-step
  const char* ga0 = (const char*)(Ab + (size_t)(bm0 + (t >> 2)) * KDIM) + (t & 3) * 16;
  const char* ga1 = ga0 + (size_t)64 * KDIM * 2;
  const char* gb0 = (const char*)(Bb + (size_t)(bn0 + (t >> 2)) * KDIM) + (t & 3) * 16;
  const char* gb1 = gb0 + (size_t)64 * KDIM * 2;
  char* la0 = (char*)ldsA + t * 16;
  char* la1 = (char*)ldsA + 4096 + t * 16;
  char* lb0 = (char*)ldsB + t * 16;
  char* lb1 = (char*)ldsB + 4096 + t * 16;

  const char* afp[4];
  const char* bfp[4];
  #pragma unroll
  for (int i = 0; i < 4; i++) {
    afp[i] = (const char*)ldsA + (wm * 64 + i * 16 + lc) * 64 + kg;
    bfp[i] = (const char*)ldsB + (wn * 64 + i * 16 + lc) * 64 + kg;
  }

  #pragma unroll
  for (int mi = 0; mi < 4; mi++)
    #pragma unroll
    for (int ni = 0; ni < 4; ni++)
      acc[mi][ni] = (floatx4){0.f, 0.f, 0.f, 0.f};

  for (int k0 = 0; k0 < KDIM; k0 += 32) {
    __syncthreads();                  // all waves done reading previous tile
    async_copy16(ga0, la0);
    async_copy16(ga1, la1);
    async_copy16(gb0, lb0);
    async_copy16(gb1, lb1);
    ga0 += 64; ga1 += 64; gb0 += 64; gb1 += 64;
    __syncthreads();                  // drains vmcnt(0): DMA complete

    short8 af[4], bfr[4];
    #pragma unroll
    for (int i = 0; i < 4; i++) af[i] = *(const short8*)(afp[i]);
    #pragma unroll
    for (int i = 0; i < 4; i++) bfr[i] = *(const short8*)(bfp[i]);
    #pragma unroll
    for (int mi = 0; mi < 4; mi++)
      #pragma unroll
      for (int ni = 0; ni < 4; ni++)
        acc[mi][ni] = __builtin_amdgcn_mfma_f32_16x16x32_bf16(af[mi], bfr[ni],
                                                              acc[mi][ni], 0, 0, 0);
  }
}

// GEMM1: P = exp(tanh(Q K + b)), bf16; row sums (of the bf16-rounded P,
// so normalization is exact for the rounded weights) via atomics.
__global__ void gemm_qk(const ushort* __restrict__ Q, const ushort* __restrict__ Kt,
                        const float* __restrict__ bias, ushort* __restrict__ P,
                        float* __restrict__ lsum) {
  __shared__ ushort ldsA[128 * 32];
  __shared__ ushort ldsB[128 * 32];
  const int z   = blockIdx.z;
  const int bm0 = blockIdx.y * 128;
  const int bn0 = blockIdx.x * 128;

  floatx4 acc[4][4];
  gemm_core<D_>(Q + (size_t)z * TQ_ * D_, Kt + (size_t)z * TK_ * D_,
                ldsA, ldsB, bm0, bn0, acc);

  const int lane = threadIdx.x & 63;
  const int w    = threadIdx.x >> 6;
  const int wm   = w >> 1, wn = w & 1;
  const int lc   = lane & 15;
  ushort* Pb = P + (size_t)z * TQ_ * TK_;
  float*  lz = lsum + z * TQ_;

  #pragma unroll
  for (int mi = 0; mi < 4; mi++) {
    int grow = bm0 + wm * 64 + mi * 16 + ((lane >> 4) << 2);  // + r
    float rs[4] = {0.f, 0.f, 0.f, 0.f};
    #pragma unroll
    for (int ni = 0; ni < 4; ni++) {
      int gcol = bn0 + wn * 64 + ni * 16 + lc;
      float bj = bias[gcol];
      #pragma unroll
      for (int r = 0; r < 4; r++) {
        float s = acc[mi][ni][r] + bj;
        // tanh(s) = 1 - 2/(e^{2s}+1); safe at +/-inf. exp(tanh) in [0.37,2.72]
        // => softmax needs no max subtraction.
        float tnh = 1.f - 2.f / (__expf(2.f * s) + 1.f);
        float p   = __expf(tnh);
        ushort pu = f2bf(p);
        Pb[(size_t)(grow + r) * TK_ + gcol] = pu;
        rs[r] += bf2f(pu);
      }
    }
    #pragma unroll
    for (int r = 0; r < 4; r++) {
      rs[r] += __shfl_xor(rs[r], 1, 64);
      rs[r] += __shfl_xor(rs[r], 2, 64);
      rs[r] += __shfl_xor(rs[r], 4, 64);
      rs[r] += __shfl_xor(rs[r], 8, 64);
    }
    if (lc == 0) {
      #pragma unroll
      for (int r = 0; r < 4; r++) atomicAdd(&lz[grow + r], rs[r]);
    }
  }
}

// GEMM2: out = (P Vt^T) / lsum, fp32 out
__global__ void gemm_pv(const ushort* __restrict__ P, const ushort* __restrict__ Vt,
                        const float* __restrict__ lsum, float* __restrict__ out) {
  __shared__ ushort ldsA[128 * 32];
  __shared__ ushort ldsB[128 * 32];
  const int z   = blockIdx.z;
  const int bm0 = blockIdx.y * 128;
  const int bn0 = blockIdx.x * 128;

  floatx4 acc[4][4];
  gemm_core<TK_>(P + (size_t)z * TQ_ * TK_, Vt + (size_t)z * DV_ * TK_,
                 ldsA, ldsB, bm0, bn0, acc);

  const int lane = threadIdx.x & 63;
  const int w    = threadIdx.x >> 6;
  const int wm   = w >> 1, wn = w & 1;
  const int lc   = lane & 15;
  float* ob = out + (size_t)z * TQ_ * DV_;
  const float* lz = lsum + z * TQ_;

  #pragma unroll
  for (int mi = 0; mi < 4; mi++) {
    int grow = bm0 + wm * 64 + mi * 16 + ((lane >> 4) << 2);
    float linv[4];
    #pragma unroll
    for (int r = 0; r < 4; r++) linv[r] = 1.f / lz[grow + r];
    #pragma unroll
    for (int ni = 0; ni < 4; ni++) {
      int gcol = bn0 + wn * 64 + ni * 16 + lc;
      #pragma unroll
      for (int r = 0; r < 4; r++)
        ob[(size_t)(grow + r) * DV_ + gcol] = acc[mi][ni][r] * linv[r];
    }
  }
}

// ---------------- launch ----------------
// Workspace layout (bytes):
//   qb   @ 0         : 8*2048*1024*2 = 33554432   (Q bf16)
//   ktb  @ 33554432  : 33554432                   (K^T bf16, [TK][D])
//   vtb  @ 67108864  : 33554432                   (V^T bf16, [DV][TK])
//   P    @ 100663296 : 8*2048*2048*2 = 67108864   (exp(tanh(S)) bf16)
//   lsum @ 167772160 : 8*2048*4      = 65536      (softmax denominators)
// Total: 167837696 bytes (~160 MB)

extern "C" void kernel_launch(void* const* d_in, const int* in_sizes, int n_in,
                              void* d_out, int out_size, void* d_ws, size_t ws_size,
                              hipStream_t stream) {
  const float* q    = (const float*)d_in[0];
  const float* k    = (const float*)d_in[1];
  const float* v    = (const float*)d_in[2];
  const float* bias = (const float*)d_in[3];
  float* out = (float*)d_out;

  char* ws = (char*)d_ws;
  ushort* qb   = (ushort*)(ws);
  ushort* ktb  = (ushort*)(ws + 33554432);
  ushort* vtb  = (ushort*)(ws + 67108864);
  ushort* P    = (ushort*)(ws + 100663296);
  float*  lsum = (float*)(ws + 167772160);

  hipMemsetAsync(lsum, 0, B_ * TQ_ * sizeof(float), stream);

  int n4q = B_ * TQ_ * D_ / 4;
  cvt_bf16<<<dim3(n4q / 256), dim3(256), 0, stream>>>((const float4*)q, (ushort4*)qb, n4q);
  // k: [D][TK] -> ktb [TK][D]
  transpose_cvt<<<dim3(TK_ / 32, D_ / 32, B_), dim3(32, 8), 0, stream>>>(k, ktb, D_, TK_);
  // v: [TK][DV] -> vtb [DV][TK]
  transpose_cvt<<<dim3(DV_ / 32, TK_ / 32, B_), dim3(32, 8), 0, stream>>>(v, vtb, TK_, DV_);

  gemm_qk<<<dim3(TK_ / 128, TQ_ / 128, B_), dim3(256), 0, stream>>>(qb, ktb, bias, P, lsum);
  gemm_pv<<<dim3(DV_ / 128, TQ_ / 128, B_), dim3(256), 0, stream>>>(P, vtb, lsum, out);
}